// Round 9
// baseline (246.604 us; speedup 1.0000x reference)
//
#include <hip/hip_runtime.h>
#include <hip/hip_bf16.h>

typedef __bf16 bf16_t;
typedef __bf16 bf16x8 __attribute__((ext_vector_type(8)));
typedef __bf16 bf16x4v __attribute__((ext_vector_type(4)));
typedef float f32x4 __attribute__((ext_vector_type(4)));

typedef const __attribute__((address_space(3))) bf16_t* lds_cptr;

// ---------------------------------------------------------------------------
// fused fp32 -> bf16 cast, 1 float4 per thread (fully coalesced 16B read /
// 8B write per lane).
// ---------------------------------------------------------------------------
__global__ __launch_bounds__(256) void cast3_f32_to_bf16(
    const float4* __restrict__ a, bf16x4v* __restrict__ ao, int na4,
    const float4* __restrict__ b, bf16x4v* __restrict__ bo, int nb4,
    const float4* __restrict__ c, bf16x4v* __restrict__ co, int nc4) {
  int i = blockIdx.x * blockDim.x + threadIdx.x;
  const float4* in;
  bf16x4v* out;
  int j;
  if (i < na4) {
    in = a; out = ao; j = i;
  } else if (i < na4 + nb4) {
    in = b; out = bo; j = i - na4;
  } else if (i < na4 + nb4 + nc4) {
    in = c; out = co; j = i - na4 - nb4;
  } else {
    return;
  }
  float4 f = in[j];
  bf16x4v o;
  o[0] = (bf16_t)f.x; o[1] = (bf16_t)f.y;
  o[2] = (bf16_t)f.z; o[3] = (bf16_t)f.w;
  out[j] = o;
}

// ---------------------------------------------------------------------------
// async global->LDS, 16B per lane. LDS dest = wave-uniform base + lane*16.
// ---------------------------------------------------------------------------
__device__ __forceinline__ void gload_lds16(const bf16_t* g, bf16_t* l) {
  __builtin_amdgcn_global_load_lds(
      (const __attribute__((address_space(1))) void*)g,
      (__attribute__((address_space(3))) void*)l,
      16, 0, 0);
}

// No "memory" clobber on waitcnt asm (a clobber re-attracts a compiler
// vmcnt(0) DMA drain -- round-3 lesson, -14us/GEMM). Ordering: volatile asm
// mutual program order + sched_barrier(0) fences for MFMA (rule #18).
template <int N>
__device__ __forceinline__ void vmwait() {
  asm volatile("s_waitcnt vmcnt(%0)" :: "i"(N));
}

template <int N>
__device__ __forceinline__ void lgkmwait() {
  asm volatile("s_waitcnt lgkmcnt(%0)" :: "i"(N));
}

// inline-asm ds_read_b128: dst[I] <- LDS[p + BASE + I*1024 bytes].
// (fragment row-block stride = 16 rows x 32 elems x 2B = 1024 B)
template <int I, int N, int BASE>
__device__ __forceinline__ void ldsr(bf16x8* dst, lds_cptr p) {
  if constexpr (I < N) {
    asm volatile("ds_read_b128 %0, %1 offset:%2"
                 : "=v"(dst[I]) : "v"(p), "i"(BASE + I * 1024));
    ldsr<I + 1, N, BASE>(dst, p);
  }
}

// one 16-MFMA cluster: acc rows [R0, R0+4) x 4 cols.
template <int R0, int FR>
__device__ __forceinline__ void mfma_clu(const bf16x8 (&aq)[4],
                                         const bf16x8 (&bq)[4],
                                         f32x4 (&acc)[FR][4]) {
#pragma unroll
  for (int i = 0; i < 4; ++i)
#pragma unroll
    for (int j = 0; j < 4; ++j)
      acc[R0 + i][j] = __builtin_amdgcn_mfma_f32_16x16x32_bf16(
          aq[i], bq[j], acc[R0 + i][j], 0, 0, 0);
}

// ---------------------------------------------------------------------------
// FINE-PHASE pipelined GEMM (m201-style): C = A[M,K]*B[N,K]^T + bias,
// optional fused swish. BM=256 x BN, 512 threads (8 waves), 16x16x32 MFMA.
// K in subtiles of 32, ring of 4 LDS sub-buffers (buf = s&3), stage depth 3.
//
// SMALL read batches paired with 16-MFMA clusters between barrier pairs
// (round 5's single mega-phase made all 8 waves dump a 96-deep ds_read
// convoy at once; LDS delivery and MFMA then ran back-to-back with no
// overlap -- body time == LDS_time + MFMA_time. Fine phasing paces LDS
// demand so delivery interleaves with compute: m196's lever).
//
// GEMM1 (FR=8, RH=2), per subtile s two phases:
//  ph(rh0): stage A(s+3) [2 gloads]; read B[s&3] (4) + A rows0-3 (4);
//           vmcnt(4); BAR; lgkm(0); 16 MFMA (rows 0-3); BAR
//  ph(rh1): stage B(s+3) [2 gloads]; read A rows4-7 (4);
//           vmcnt(4); BAR; lgkm(0); 16 MFMA (rows 4-7); BAR
// GEMM2 (FR=4, RH=1), one phase: stage A+B(s+3) [3 gloads]; read B+A (8);
//           vmcnt(6); BAR; lgkm(0); 16 MFMA; BAR
//
// Wait ledger (stage units issued one per phase, in order): vmcnt leaves
// the last 2 stage-phases outstanding (GEMM1: 4 loads, GEMM2: 6), so every
// unit is forced complete ~2 phases (~1400cy) after issue and >=1 phase
// before its first read -- own-wait BEFORE a barrier collectivizes the
// per-wave DMA guarantee across waves. Never vmcnt(0) in the loop.
// Overwrite safety: phase lgkm(0) drains reads of buf b before its end
// barrier; stage into buf (s+3)&3=(s-1)&3 happens after that barrier.
// Tail stages wrap mod NS into dead buffers (uniform counts).
// LDS: [row][32] bf16 rows (64B), 16B chunk swizzle phys = chunk ^
// (((row&15)>>1)&3); staged linearly via pre-swizzled per-lane global src
// (verified 0 bank conflicts, rounds 5-7). Requires M%256==0, N%BN==0,
// K%128==0.
// ---------------------------------------------------------------------------
#define PHASE_R0(b_, sw_)                                                     \
  {                                                                           \
    stageA(sw_);                                                              \
    lds_cptr pa = sA3 + (b_) * (256 * 32) + aoff;                             \
    lds_cptr pb = sB3 + (b_) * (BN * 32) + boff;                              \
    ldsr<0, 4, 0>(bq, pb);                                                    \
    ldsr<0, 4, 0>(aq, pa);                                                    \
    vmwait<LEAVE>();                                                          \
    __builtin_amdgcn_s_barrier();                                             \
    lgkmwait<0>();                                                            \
    __builtin_amdgcn_sched_barrier(0);                                        \
    __builtin_amdgcn_s_setprio(1);                                            \
    mfma_clu<0, FR>(aq, bq, acc);                                             \
    __builtin_amdgcn_s_setprio(0);                                            \
    __builtin_amdgcn_s_barrier();                                             \
  }

#define PHASE_R1(b_, sw_)                                                     \
  {                                                                           \
    stageB(sw_);                                                              \
    lds_cptr pa = sA3 + (b_) * (256 * 32) + aoff;                             \
    ldsr<0, 4, 4 * 1024>(aq, pa);                                             \
    vmwait<LEAVE>();                                                          \
    __builtin_amdgcn_s_barrier();                                             \
    lgkmwait<0>();                                                            \
    __builtin_amdgcn_sched_barrier(0);                                        \
    __builtin_amdgcn_s_setprio(1);                                            \
    mfma_clu<4, FR>(aq, bq, acc);                                             \
    __builtin_amdgcn_s_setprio(0);                                            \
    __builtin_amdgcn_s_barrier();                                             \
  }

#define PHASE_G2(b_, sw_)                                                     \
  {                                                                           \
    stageA(sw_);                                                              \
    stageB(sw_);                                                              \
    lds_cptr pa = sA3 + (b_) * (256 * 32) + aoff;                             \
    lds_cptr pb = sB3 + (b_) * (BN * 32) + boff;                              \
    ldsr<0, 4, 0>(bq, pb);                                                    \
    ldsr<0, 4, 0>(aq, pa);                                                    \
    vmwait<LEAVE>();                                                          \
    __builtin_amdgcn_s_barrier();                                             \
    lgkmwait<0>();                                                            \
    __builtin_amdgcn_sched_barrier(0);                                        \
    __builtin_amdgcn_s_setprio(1);                                            \
    mfma_clu<0, FR>(aq, bq, acc);                                             \
    __builtin_amdgcn_s_setprio(0);                                            \
    __builtin_amdgcn_s_barrier();                                             \
  }

#define SUBTILE(b_, sw_)                                                      \
  if constexpr (RH == 2) {                                                    \
    PHASE_R0(b_, sw_)                                                         \
    PHASE_R1(b_, sw_)                                                         \
  } else {                                                                    \
    PHASE_G2(b_, sw_)                                                         \
  }

template <int BN, int WM, int WN, bool SWISH>
__global__ __launch_bounds__(512, 2) void gemm_fp(
    const bf16_t* __restrict__ A, const bf16_t* __restrict__ B,
    const float* __restrict__ bias, void* __restrict__ Cout,
    int M, int N, int K, int XW, int px, int py) {
  constexpr int BM = 256;
  constexpr int WR = BM / WM;      // wave rows (128 or 64)
  constexpr int WC = BN / WN;      // wave cols (64)
  constexpr int FR = WR / 16;      // frag rows per wave (8 or 4)
  constexpr int RH = FR / 4;       // row-half clusters per subtile (2 or 1)
  constexpr int ACALLS = BM / 128;       // gloads per A stage (2)
  constexpr int BCALLS = BN / 128;       // 2 (BN=256) or 1 (BN=128)
  constexpr int LEAVE = (RH == 2) ? 4 : 6;  // leave 2 stage-phases in flight

  const int tid = threadIdx.x;
  const int wave = tid >> 6;
  const int lane = tid & 63;

  // ---- XCD-aware block swizzle (grid % 8 == 0 in both uses) ----
  const int bid = blockIdx.x;
  const int xcd = bid & 7;
  const int idx = bid >> 3;
  const int cx = xcd % XW;
  const int cy = xcd / XW;
  const int bx = cx * px + idx % px;
  const int by = cy * py + idx / px;
  const int tileM = by * BM;
  const int tileN = bx * BN;

  __shared__ __align__(16) bf16_t sA[4 * 256 * 32];
  __shared__ __align__(16) bf16_t sB[4 * BN * 32];
  lds_cptr sA3 = (lds_cptr)sA;
  lds_cptr sB3 = (lds_cptr)sB;

  // ---- staging geometry: one call = 512 thr x 16B = 128 rows x 32 cols ----
  // lane -> row lane>>2, phys chunk lane&3 (linear LDS);
  // fetches GLOBAL chunk (lane&3) ^ ((lane>>3)&3)  [= chunk ^ ((row&15)>>1)&3]
  const int srow = (wave << 4) + (lane >> 2);              // 0..127
  const int sgc = ((lane & 3) ^ ((lane >> 3) & 3)) << 3;   // 0..24, global col
  const bf16_t* gA = A + (size_t)(tileM + srow) * K + sgc;
  const bf16_t* gB = B + (size_t)(tileN + srow) * K + sgc;
  bf16_t* lA = sA + (wave << 9);  // wave-uniform LDS base (wave*16 rows)
  bf16_t* lB = sB + (wave << 9);

  auto stageA = [&](int s) {
    bf16_t* l = lA + (s & 3) * (256 * 32);
    const bf16_t* g = gA + s * 32;
#pragma unroll
    for (int c = 0; c < ACALLS; ++c)
      gload_lds16(g + (size_t)(c * 128) * K, l + c * 128 * 32);
  };
  auto stageB = [&](int s) {
    bf16_t* l = lB + (s & 3) * (BN * 32);
    const bf16_t* g = gB + s * 32;
#pragma unroll
    for (int c = 0; c < BCALLS; ++c)
      gload_lds16(g + (size_t)(c * 128) * K, l + c * 128 * 32);
  };

  // ---- fragment read offsets (within one sub-buffer, elements) ----
  const int wr = wave / WN;
  const int wc = wave % WN;
  const int fr = lane & 15;
  const int pc = (lane >> 4) ^ ((fr >> 1) & 3);  // swizzled phys chunk
  const int aoff = (wr * WR + fr) * 32 + pc * 8;
  const int boff = (wc * WC + fr) * 32 + pc * 8;

  f32x4 acc[FR][4] = {};
  bf16x8 aq[4], bq[4];

  const int NS = K >> 5;  // 32-wide K subtiles; NS % 4 == 0

  // ---- prologue: stage subtiles 0,1,2; force 0,1; sync ----
  stageA(0); stageB(0);
  stageA(1); stageB(1);
  stageA(2); stageB(2);
  vmwait<LEAVE>();
  __builtin_amdgcn_s_barrier();

  // ---- main loop: 4 subtiles per iteration (static buf index) ----
  for (int os = 0; os < NS; os += 4) {
    int w0 = os + 3;     if (w0 >= NS) w0 -= NS;
    int w1 = os + 4;     if (w1 >= NS) w1 -= NS;
    int w2 = os + 5;     if (w2 >= NS) w2 -= NS;
    int w3 = os + 6;     if (w3 >= NS) w3 -= NS;
    SUBTILE(0, w0)
    SUBTILE(1, w1)
    SUBTILE(2, w2)
    SUBTILE(3, w3)
  }
  lgkmwait<0>();
  __builtin_amdgcn_sched_barrier(0);

  // ---- epilogue: C/D layout col = lane&15, row = (lane>>4)*4 + reg ----
  // j INNERMOST: stores filling one cache line are adjacent so L2 merges
  // (round-5: WRITE_SIZE dropped to the ideal 64 MB).
  const int cRow0 = tileM + wr * WR + ((lane >> 4) << 2);
  const int cCol0 = tileN + wc * WC + (lane & 15);
  float bv[4];
#pragma unroll
  for (int j = 0; j < 4; ++j) bv[j] = bias[cCol0 + j * 16];
#pragma unroll
  for (int i = 0; i < FR; ++i) {
#pragma unroll
    for (int r = 0; r < 4; ++r) {
      const size_t row = (size_t)(cRow0 + i * 16 + r);
#pragma unroll
      for (int j = 0; j < 4; ++j) {
        float h = acc[i][j][r] + bv[j];
        if constexpr (SWISH) {
          float h3 = h * h * h;
          float sw = h * (0.5f + 0.25f * h - 0.0208f * h3);
          ((bf16_t*)Cout)[row * N + cCol0 + j * 16] = (bf16_t)sw;
        } else {
          ((float*)Cout)[row * N + cCol0 + j * 16] = h;
        }
      }
    }
  }
}

// ---------------------------------------------------------------------------
// launch
// ---------------------------------------------------------------------------
extern "C" void kernel_launch(void* const* d_in, const int* in_sizes, int n_in,
                              void* d_out, int out_size, void* d_ws,
                              size_t ws_size, hipStream_t stream) {
  const float* X  = (const float*)d_in[0];  // [B,S,D] = [M,D]
  const float* W1 = (const float*)d_in[1];  // [F,D]
  const float* b1 = (const float*)d_in[2];  // [F]
  const float* W2 = (const float*)d_in[3];  // [D,F]
  const float* b2 = (const float*)d_in[4];  // [D]
  float* out = (float*)d_out;               // [M,D]

  const int F = in_sizes[2];      // 4096
  const int D = in_sizes[4];      // 1024
  const int M = in_sizes[0] / D;  // 8192

  // workspace layout (bf16): Xb[M*D] | W1b[F*D] | W2b[D*F] | SW[M*F]
  bf16_t* Xb  = (bf16_t*)d_ws;
  bf16_t* W1b = Xb + (size_t)M * D;
  bf16_t* W2b = W1b + (size_t)F * D;
  bf16_t* SW  = W2b + (size_t)D * F;

  const int nX = (M * D) / 4, nW1 = (F * D) / 4, nW2 = (D * F) / 4;
  const int nTot = nX + nW1 + nW2;
  cast3_f32_to_bf16<<<(nTot + 255) / 256, 256, 0, stream>>>(
      (const float4*)X, (bf16x4v*)Xb, nX,
      (const float4*)W1, (bf16x4v*)W1b, nW1,
      (const float4*)W2, (bf16x4v*)W2b, nW2);

  // GEMM1: SW[M,F] = swish(Xb[M,D] @ W1b[F,D]^T + b1)   (bf16 out)
  // 256x256 tiles: gx = F/256 = 16, gy = M/256 = 32; XCDs as 2x4 -> 8x8 patch
  {
    const int gx = F / 256, gy = M / 256;
    const int XW = 2, XH = 4;
    const int px = gx / XW, py = gy / XH;
    gemm_fp<256, 2, 4, true><<<gx * gy, 512, 0, stream>>>(
        Xb, W1b, b1, (void*)SW, M, F, D, XW, px, py);
  }

  // GEMM2: out[M,D] = SW[M,F] @ W2b[D,F]^T + b2         (fp32 out)
  // 256x128 tiles: gx = D/128 = 8, gy = M/256 = 32; XCDs as 1x8 -> 8x4 patch
  {
    const int gx = D / 128, gy = M / 256;
    const int XW = 1, XH = 8;
    const int px = gx / XW, py = gy / XH;
    gemm_fp<128, 4, 2, false><<<gx * gy, 512, 0, stream>>>(
        SW, W2b, b2, (void*)out, M, D, F, XW, px, py);
  }
}